// Round 1
// baseline (115.672 us; speedup 1.0000x reference)
//
#include <hip/hip_runtime.h>
#include <hip/hip_bf16.h>

#define SLEN 8192
#define EDIM 1024

// ---------------- helpers ----------------

__device__ inline float waveReduceSum64(float v) {
#pragma unroll
    for (int off = 32; off; off >>= 1) v += __shfl_xor(v, off);
    return v;
}

// full-block (1024 threads) sum, result broadcast to all threads
__device__ inline float blockSum1024(float v, float* lds) {
    v = waveReduceSum64(v);
    int w = threadIdx.x >> 6, ln = threadIdx.x & 63;
    __syncthreads();
    if (ln == 0) lds[w] = v;
    __syncthreads();
    float s = (ln < 16) ? lds[ln] : 0.f;
#pragma unroll
    for (int off = 8; off; off >>= 1) s += __shfl_xor(s, off);
    s = __shfl(s, 0);
    return s;
}

// ---------------- QKV GEMV (split-K partials) ----------------
// grid (12, 8), block 256. colgroup = blockIdx.x; matrix = colgroup>>2.
__global__ __launch_bounds__(256) void qkv_partial(
    const float* __restrict__ Wq, const float* __restrict__ Wk,
    const float* __restrict__ Wv, const float* __restrict__ x,
    float* __restrict__ part) {
    int cg = blockIdx.x;
    int m = cg >> 2;
    const float* W = (m == 0) ? Wq : ((m == 1) ? Wk : Wv);
    int col = (cg & 3) * 256 + threadIdx.x;
    int r0 = blockIdx.y * 128;
    float acc = 0.f;
#pragma unroll 8
    for (int r = 0; r < 128; ++r)
        acc = fmaf(x[r0 + r], W[(r0 + r) * EDIM + col], acc);
    part[(m * 8 + blockIdx.y) * EDIM + col] = acc;
}

// grid 3, block 1024
__global__ __launch_bounds__(1024) void qkv_combine(
    const float* __restrict__ part,
    const float* __restrict__ bq, const float* __restrict__ bk,
    const float* __restrict__ bv,
    float* __restrict__ qs, float* __restrict__ ki, float* __restrict__ vi) {
    int m = blockIdx.x, t = threadIdx.x;
    float v = 0.f;
#pragma unroll
    for (int sl = 0; sl < 8; ++sl) v += part[(m * 8 + sl) * EDIM + t];
    if (m == 0) qs[t] = (v + bq[t]) * 0.125f;   // pre-scale q by 1/sqrt(64)
    else if (m == 1) ki[t] = v + bk[t];
    else vi[t] = v + bv[t];
}

// ---------------- fused cache-shift + flash attention (partials) ----------------
// grid 256, block 128 (2 waves/block). wave id in [0,512), 16 positions each.
__global__ __launch_bounds__(128) void attn_main(
    const float* __restrict__ cache,   // [2, S, 1024]
    const float* __restrict__ qs,      // q/8 [1024]
    const float* __restrict__ ki, const float* __restrict__ vi,
    float* __restrict__ nv,            // new v cache [S,1024]
    float* __restrict__ nk,            // new k cache [S,1024]
    float* __restrict__ pm, float* __restrict__ pl, float* __restrict__ pacc) {
    int tid = threadIdx.x;
    int wid = blockIdx.x * 2 + (tid >> 6);
    int ld = tid & 63;

    float4 q4[4];
#pragma unroll
    for (int it = 0; it < 4; ++it)
        q4[it] = *(const float4*)(qs + it * 256 + ld * 4);

    float m4[4], l4[4];
    float4 a4[4];
#pragma unroll
    for (int it = 0; it < 4; ++it) {
        m4[it] = -1e30f; l4[it] = 0.f;
        a4[it] = make_float4(0.f, 0.f, 0.f, 0.f);
    }

    int s0 = wid * 16;
    for (int p = 0; p < 16; ++p) {
        int s = s0 + p;
        const float* vsrc;
        const float* ksrc;
        if (s < SLEN - 1) {
            vsrc = cache + (size_t)(s + 1) * EDIM;
            ksrc = cache + (size_t)SLEN * EDIM + (size_t)(s + 1) * EDIM;
        } else {
            vsrc = vi; ksrc = ki;
        }
        float4 vv[4], kv[4];
        float sc[4];
        bool nz = false;
#pragma unroll
        for (int it = 0; it < 4; ++it) {
            vv[it] = *(const float4*)(vsrc + it * 256 + ld * 4);
            kv[it] = *(const float4*)(ksrc + it * 256 + ld * 4);
            *(float4*)(nv + (size_t)s * EDIM + it * 256 + ld * 4) = vv[it];
            *(float4*)(nk + (size_t)s * EDIM + it * 256 + ld * 4) = kv[it];
            nz = nz || (vv[it].x != 0.f) || (vv[it].y != 0.f) ||
                 (vv[it].z != 0.f) || (vv[it].w != 0.f);
            float d = q4[it].x * kv[it].x + q4[it].y * kv[it].y +
                      q4[it].z * kv[it].z + q4[it].w * kv[it].w;
            d += __shfl_xor(d, 1);
            d += __shfl_xor(d, 2);
            d += __shfl_xor(d, 4);
            d += __shfl_xor(d, 8);
            sc[it] = d;   // score for head it*4 + (ld>>4), broadcast in 16-lane group
        }
        if (__ballot(nz) != 0ull) {
#pragma unroll
            for (int it = 0; it < 4; ++it) {
                float mo = m4[it];
                float mn = fmaxf(mo, sc[it]);
                float sl = __expf(mo - mn);
                float w  = __expf(sc[it] - mn);
                l4[it] = l4[it] * sl + w;
                a4[it].x = a4[it].x * sl + w * vv[it].x;
                a4[it].y = a4[it].y * sl + w * vv[it].y;
                a4[it].z = a4[it].z * sl + w * vv[it].z;
                a4[it].w = a4[it].w * sl + w * vv[it].w;
                m4[it] = mn;
            }
        }
    }
    // write per-wave partials
#pragma unroll
    for (int it = 0; it < 4; ++it) {
        int h = it * 4 + (ld >> 4);
        if ((ld & 15) == 0) {
            pm[wid * 16 + h] = m4[it];
            pl[wid * 16 + h] = l4[it];
        }
        *(float4*)(pacc + (size_t)wid * EDIM + it * 256 + ld * 4) = a4[it];
    }
}

// 1 block, 1024 threads: wave h = tid>>6, lane = d
__global__ __launch_bounds__(1024) void attn_combine(
    const float* __restrict__ pm, const float* __restrict__ pl,
    const float* __restrict__ pacc, float* __restrict__ values) {
    int h = threadIdx.x >> 6, ld = threadIdx.x & 63;
    float mm = -1e30f;
    for (int p = ld; p < 512; p += 64) mm = fmaxf(mm, pm[p * 16 + h]);
#pragma unroll
    for (int off = 32; off; off >>= 1) mm = fmaxf(mm, __shfl_xor(mm, off));
    float ll = 0.f;
    for (int p = ld; p < 512; p += 64) ll += pl[p * 16 + h] * __expf(pm[p * 16 + h] - mm);
    ll = waveReduceSum64(ll);
    float a = 0.f;
    for (int p = 0; p < 512; ++p)
        a += pacc[(size_t)p * EDIM + h * 64 + ld] * __expf(pm[p * 16 + h] - mm);
    values[h * 64 + ld] = a / ll;
}

// ---------------- generic GEMV partial (split-K) ----------------
// grid (4, 8), block 256
__global__ __launch_bounds__(256) void gemv_partial(
    const float* __restrict__ W, const float* __restrict__ xin,
    float* __restrict__ part) {
    int col = blockIdx.x * 256 + threadIdx.x;
    int r0 = blockIdx.y * 128;
    float acc = 0.f;
#pragma unroll 8
    for (int r = 0; r < 128; ++r)
        acc = fmaf(xin[r0 + r], W[(r0 + r) * EDIM + col], acc);
    part[blockIdx.y * EDIM + col] = acc;
}

// 1 block 1024: out = relu(bias + sum partials)
__global__ __launch_bounds__(1024) void combine_relu(
    const float* __restrict__ part, const float* __restrict__ bias,
    float* __restrict__ out) {
    int t = threadIdx.x;
    float v = bias[t];
#pragma unroll
    for (int sl = 0; sl < 8; ++sl) v += part[sl * EDIM + t];
    out[t] = fmaxf(v, 0.f);
}

// 1 block 1024: r = resid + bias + sum partials; out = LN(r)*g + b
__global__ __launch_bounds__(1024) void combine_ln(
    const float* __restrict__ part, const float* __restrict__ bias,
    const float* __restrict__ resid, const float* __restrict__ g,
    const float* __restrict__ b, float* __restrict__ out) {
    __shared__ float lds[32];
    int t = threadIdx.x;
    float v = bias[t];
#pragma unroll
    for (int sl = 0; sl < 8; ++sl) v += part[sl * EDIM + t];
    float r = resid[t] + v;
    float mean = blockSum1024(r, lds) * (1.f / 1024.f);
    float d = r - mean;
    float var = blockSum1024(d * d, lds) * (1.f / 1024.f);
    out[t] = d * rsqrtf(var + 1e-6f) * g[t] + b[t];
}

// ---------------- launch ----------------
extern "C" void kernel_launch(void* const* d_in, const int* in_sizes, int n_in,
                              void* d_out, int out_size, void* d_ws, size_t ws_size,
                              hipStream_t stream) {
    const float* x     = (const float*)d_in[0];
    const float* cache = (const float*)d_in[1];
    const float* Wv    = (const float*)d_in[2];
    const float* bv    = (const float*)d_in[3];
    const float* Wq    = (const float*)d_in[4];
    const float* bq    = (const float*)d_in[5];
    const float* Wk    = (const float*)d_in[6];
    const float* bk    = (const float*)d_in[7];
    const float* Wo    = (const float*)d_in[8];
    const float* bo    = (const float*)d_in[9];
    const float* W1    = (const float*)d_in[10];
    const float* b1    = (const float*)d_in[11];
    const float* W2    = (const float*)d_in[12];
    const float* b2    = (const float*)d_in[13];
    const float* ln1s  = (const float*)d_in[14];
    const float* ln1b  = (const float*)d_in[15];
    const float* ln2s  = (const float*)d_in[16];
    const float* ln2b  = (const float*)d_in[17];

    float* out = (float*)d_out;
    float* nv = out + 1024;                              // new cache v half
    float* nk = out + 1024 + (size_t)SLEN * EDIM;        // new cache k half

    float* w      = (float*)d_ws;
    float* qs     = w;             // 1024 (q * 1/8)
    float* ki     = w + 1024;      // 1024
    float* vi     = w + 2048;      // 1024
    float* qkvp   = w + 3072;      // 3*8*1024
    float* pm     = w + 27648;     // 512*16
    float* pl     = w + 35840;     // 512*16
    float* pacc   = w + 44032;     // 512*1024
    float* values = w + 568320;    // 1024
    float* h1     = w + 569344;    // 1024
    float* hff    = w + 570368;    // 1024
    float* gp1    = w + 571392;    // 8*1024
    float* gp2    = w + 579584;    // 8*1024
    float* gp3    = w + 587776;    // 8*1024

    qkv_partial<<<dim3(12, 8), 256, 0, stream>>>(Wq, Wk, Wv, x, qkvp);
    qkv_combine<<<3, 1024, 0, stream>>>(qkvp, bq, bk, bv, qs, ki, vi);
    attn_main<<<256, 128, 0, stream>>>(cache, qs, ki, vi, nv, nk, pm, pl, pacc);
    attn_combine<<<1, 1024, 0, stream>>>(pm, pl, pacc, values);
    gemv_partial<<<dim3(4, 8), 256, 0, stream>>>(Wo, values, gp1);
    combine_ln<<<1, 1024, 0, stream>>>(gp1, bo, x, ln1s, ln1b, h1);
    gemv_partial<<<dim3(4, 8), 256, 0, stream>>>(W1, h1, gp2);
    combine_relu<<<1, 1024, 0, stream>>>(gp2, b1, hff);
    gemv_partial<<<dim3(4, 8), 256, 0, stream>>>(W2, hff, gp3);
    combine_ln<<<1, 1024, 0, stream>>>(gp3, b2, h1, ln2s, ln2b, out);
}

// Round 2
// 99.201 us; speedup vs baseline: 1.1660x; 1.1660x over previous
//
#include <hip/hip_runtime.h>
#include <hip/hip_bf16.h>

#define SLEN 8192
#define EDIM 1024

// ---------------- helpers ----------------

__device__ inline float waveReduceSum64(float v) {
#pragma unroll
    for (int off = 32; off; off >>= 1) v += __shfl_xor(v, off);
    return v;
}

__device__ inline float blockSum1024(float v, float* lds) {
    v = waveReduceSum64(v);
    int w = threadIdx.x >> 6, ln = threadIdx.x & 63;
    __syncthreads();
    if (ln == 0) lds[w] = v;
    __syncthreads();
    float s = (ln < 16) ? lds[ln] : 0.f;
#pragma unroll
    for (int off = 8; off; off >>= 1) s += __shfl_xor(s, off);
    s = __shfl(s, 0);
    return s;
}

// ---------------- QKV GEMV (split-K partials) ----------------
// grid (12, 16), block 256. cg = blockIdx.x; matrix = cg>>2. 64 rows/slice.
__global__ __launch_bounds__(256) void qkv_partial(
    const float* __restrict__ Wq, const float* __restrict__ Wk,
    const float* __restrict__ Wv, const float* __restrict__ x,
    float* __restrict__ part) {
    int cg = blockIdx.x;
    int m = cg >> 2;
    const float* W = (m == 0) ? Wq : ((m == 1) ? Wk : Wv);
    int col = (cg & 3) * 256 + threadIdx.x;
    int r0 = blockIdx.y * 64;
    float acc = 0.f;
#pragma unroll 8
    for (int r = 0; r < 64; ++r)
        acc = fmaf(x[r0 + r], W[(r0 + r) * EDIM + col], acc);
    part[((size_t)m * 16 + blockIdx.y) * EDIM + col] = acc;
}

// grid 3, block 1024
__global__ __launch_bounds__(1024) void qkv_combine(
    const float* __restrict__ part,
    const float* __restrict__ bq, const float* __restrict__ bk,
    const float* __restrict__ bv,
    float* __restrict__ qs, float* __restrict__ ki, float* __restrict__ vi) {
    int m = blockIdx.x, t = threadIdx.x;
    float v = 0.f;
#pragma unroll
    for (int sl = 0; sl < 16; ++sl) v += part[((size_t)m * 16 + sl) * EDIM + t];
    if (m == 0) qs[t] = (v + bq[t]) * 0.125f;   // pre-scale q by 1/sqrt(64)
    else if (m == 1) ki[t] = v + bk[t];
    else vi[t] = v + bv[t];
}

// ---------------- fused cache-shift + flash attention (partials) ----------------
// grid NW/4 blocks, block 256 (4 waves). Each wave handles ppw positions.
__global__ __launch_bounds__(256) void attn_main(
    const float* __restrict__ cache,   // [2, S, 1024]
    const float* __restrict__ qs,      // q/8 [1024]
    const float* __restrict__ ki, const float* __restrict__ vi,
    float* __restrict__ nv, float* __restrict__ nk,
    float* __restrict__ pm, float* __restrict__ pl, float* __restrict__ pacc,
    int ppw) {
    int tid = threadIdx.x;
    int wid = blockIdx.x * 4 + (tid >> 6);
    int ld = tid & 63;

    float4 q4[4];
#pragma unroll
    for (int it = 0; it < 4; ++it)
        q4[it] = *(const float4*)(qs + it * 256 + ld * 4);

    float m4[4], l4[4];
    float4 a4[4];
#pragma unroll
    for (int it = 0; it < 4; ++it) {
        m4[it] = -1e30f; l4[it] = 0.f;
        a4[it] = make_float4(0.f, 0.f, 0.f, 0.f);
    }

    int s0 = wid * ppw;
    for (int p = 0; p < ppw; ++p) {
        int s = s0 + p;
        const float* vsrc;
        const float* ksrc;
        if (s < SLEN - 1) {
            vsrc = cache + (size_t)(s + 1) * EDIM;
            ksrc = cache + (size_t)SLEN * EDIM + (size_t)(s + 1) * EDIM;
        } else {
            vsrc = vi; ksrc = ki;
        }
        float4 vv[4], kv[4];
        float sc[4];
        bool nz = false;
#pragma unroll
        for (int it = 0; it < 4; ++it) {
            vv[it] = *(const float4*)(vsrc + it * 256 + ld * 4);
            kv[it] = *(const float4*)(ksrc + it * 256 + ld * 4);
        }
#pragma unroll
        for (int it = 0; it < 4; ++it) {
            *(float4*)(nv + (size_t)s * EDIM + it * 256 + ld * 4) = vv[it];
            *(float4*)(nk + (size_t)s * EDIM + it * 256 + ld * 4) = kv[it];
            nz = nz || (vv[it].x != 0.f) || (vv[it].y != 0.f) ||
                 (vv[it].z != 0.f) || (vv[it].w != 0.f);
            float d = q4[it].x * kv[it].x + q4[it].y * kv[it].y +
                      q4[it].z * kv[it].z + q4[it].w * kv[it].w;
            d += __shfl_xor(d, 1);
            d += __shfl_xor(d, 2);
            d += __shfl_xor(d, 4);
            d += __shfl_xor(d, 8);
            sc[it] = d;   // score for head it*4 + (ld>>4)
        }
        if (__ballot(nz) != 0ull) {
#pragma unroll
            for (int it = 0; it < 4; ++it) {
                float mo = m4[it];
                float mn = fmaxf(mo, sc[it]);
                float sl = __expf(mo - mn);
                float w  = __expf(sc[it] - mn);
                l4[it] = l4[it] * sl + w;
                a4[it].x = a4[it].x * sl + w * vv[it].x;
                a4[it].y = a4[it].y * sl + w * vv[it].y;
                a4[it].z = a4[it].z * sl + w * vv[it].z;
                a4[it].w = a4[it].w * sl + w * vv[it].w;
                m4[it] = mn;
            }
        }
    }
#pragma unroll
    for (int it = 0; it < 4; ++it) {
        int h = it * 4 + (ld >> 4);
        if ((ld & 15) == 0) {
            pm[wid * 16 + h] = m4[it];
            pl[wid * 16 + h] = l4[it];
        }
        *(float4*)(pacc + (size_t)wid * EDIM + it * 256 + ld * 4) = a4[it];
    }
}

// stage 1 reduce: grid (16 heads, G groups), block 64. 64 partials per block.
__global__ __launch_bounds__(64) void attn_red1(
    const float* __restrict__ pm, const float* __restrict__ pl,
    const float* __restrict__ pacc,
    float* __restrict__ m2, float* __restrict__ l2, float* __restrict__ acc2) {
    int h = blockIdx.x, g = blockIdx.y, ld = threadIdx.x;
    int p0 = g * 64;
    float lm = -1e30f;
#pragma unroll 8
    for (int i = 0; i < 64; ++i) lm = fmaxf(lm, pm[(p0 + i) * 16 + h]);
    float l = 0.f, a = 0.f;
#pragma unroll 4
    for (int i = 0; i < 64; ++i) {
        float w = __expf(pm[(p0 + i) * 16 + h] - lm);
        l += w * pl[(p0 + i) * 16 + h];
        a += w * pacc[(size_t)(p0 + i) * EDIM + h * 64 + ld];
    }
    if (ld == 0) { m2[g * 16 + h] = lm; l2[g * 16 + h] = l; }
    acc2[(size_t)g * EDIM + h * 64 + ld] = a;
}

// stage 2: 1 block 1024. thread = (h, d).
__global__ __launch_bounds__(1024) void attn_red2(
    const float* __restrict__ m2, const float* __restrict__ l2,
    const float* __restrict__ acc2, float* __restrict__ values, int G) {
    int t = threadIdx.x, h = t >> 6;
    float m = -1e30f;
    for (int g = 0; g < G; ++g) m = fmaxf(m, m2[g * 16 + h]);
    float l = 0.f, a = 0.f;
    for (int g = 0; g < G; ++g) {
        float w = __expf(m2[g * 16 + h] - m);
        l += w * l2[g * 16 + h];
        a += w * acc2[(size_t)g * EDIM + t];
    }
    values[t] = a / l;
}

// ---------------- generic GEMV partial (split-K) ----------------
// grid (4, 16), block 256, 64 rows/slice
__global__ __launch_bounds__(256) void gemv_partial(
    const float* __restrict__ W, const float* __restrict__ xin,
    float* __restrict__ part) {
    int col = blockIdx.x * 256 + threadIdx.x;
    int r0 = blockIdx.y * 64;
    float acc = 0.f;
#pragma unroll 8
    for (int r = 0; r < 64; ++r)
        acc = fmaf(xin[r0 + r], W[(r0 + r) * EDIM + col], acc);
    part[(size_t)blockIdx.y * EDIM + col] = acc;
}

__global__ __launch_bounds__(1024) void combine_relu(
    const float* __restrict__ part, const float* __restrict__ bias,
    float* __restrict__ out) {
    int t = threadIdx.x;
    float v = bias[t];
#pragma unroll
    for (int sl = 0; sl < 16; ++sl) v += part[(size_t)sl * EDIM + t];
    out[t] = fmaxf(v, 0.f);
}

__global__ __launch_bounds__(1024) void combine_ln(
    const float* __restrict__ part, const float* __restrict__ bias,
    const float* __restrict__ resid, const float* __restrict__ g,
    const float* __restrict__ b, float* __restrict__ out) {
    __shared__ float lds[32];
    int t = threadIdx.x;
    float v = bias[t];
#pragma unroll
    for (int sl = 0; sl < 16; ++sl) v += part[(size_t)sl * EDIM + t];
    float r = resid[t] + v;
    float mean = blockSum1024(r, lds) * (1.f / 1024.f);
    float d = r - mean;
    float var = blockSum1024(d * d, lds) * (1.f / 1024.f);
    out[t] = d * rsqrtf(var + 1e-6f) * g[t] + b[t];
}

// ---------------- launch ----------------
extern "C" void kernel_launch(void* const* d_in, const int* in_sizes, int n_in,
                              void* d_out, int out_size, void* d_ws, size_t ws_size,
                              hipStream_t stream) {
    const float* x     = (const float*)d_in[0];
    const float* cache = (const float*)d_in[1];
    const float* Wv    = (const float*)d_in[2];
    const float* bv    = (const float*)d_in[3];
    const float* Wq    = (const float*)d_in[4];
    const float* bq    = (const float*)d_in[5];
    const float* Wk    = (const float*)d_in[6];
    const float* bk    = (const float*)d_in[7];
    const float* Wo    = (const float*)d_in[8];
    const float* bo    = (const float*)d_in[9];
    const float* W1    = (const float*)d_in[10];
    const float* b1    = (const float*)d_in[11];
    const float* W2    = (const float*)d_in[12];
    const float* b2    = (const float*)d_in[13];
    const float* ln1s  = (const float*)d_in[14];
    const float* ln1b  = (const float*)d_in[15];
    const float* ln2s  = (const float*)d_in[16];
    const float* ln2b  = (const float*)d_in[17];

    float* out = (float*)d_out;
    float* nv = out + 1024;
    float* nk = out + 1024 + (size_t)SLEN * EDIM;

    // choose attention split by available scratch
    // need (floats): 3072 + 49152 + NW*16*2 + NW*1024 + G*16*2 + G*1024
    //                + 3*1024 + 3*16*1024  where G = NW/64
    size_t ws_floats = ws_size / 4;
    int NW = 1024;
    {
        auto need = [](int nw) -> size_t {
            size_t g = nw / 64;
            return 3072 + 49152 + (size_t)nw * 32 + (size_t)nw * 1024
                   + g * 32 + g * 1024 + 3 * 1024 + 3 * 16 * 1024 + 1024;
        };
        if (ws_floats < need(1024)) NW = 512;
        if (ws_floats < need(512))  NW = 256;
    }
    int G = NW / 64;
    int PPW = SLEN / NW;

    float* w      = (float*)d_ws;
    float* qs     = w;                         // 1024
    float* ki     = qs + 1024;                 // 1024
    float* vi     = ki + 1024;                 // 1024
    float* qkvp   = vi + 1024;                 // 3*16*1024
    float* pm     = qkvp + 3 * 16 * 1024;      // NW*16
    float* pl     = pm + (size_t)NW * 16;      // NW*16
    float* pacc   = pl + (size_t)NW * 16;      // NW*1024
    float* m2     = pacc + (size_t)NW * 1024;  // G*16
    float* l2     = m2 + G * 16;               // G*16
    float* acc2   = l2 + G * 16;               // G*1024
    float* values = acc2 + (size_t)G * 1024;   // 1024
    float* h1     = values + 1024;             // 1024
    float* hff    = h1 + 1024;                 // 1024
    float* gp1    = hff + 1024;                // 16*1024
    float* gp2    = gp1 + 16 * 1024;           // 16*1024
    float* gp3    = gp2 + 16 * 1024;           // 16*1024

    qkv_partial<<<dim3(12, 16), 256, 0, stream>>>(Wq, Wk, Wv, x, qkvp);
    qkv_combine<<<3, 1024, 0, stream>>>(qkvp, bq, bk, bv, qs, ki, vi);
    attn_main<<<NW / 4, 256, 0, stream>>>(cache, qs, ki, vi, nv, nk, pm, pl, pacc, PPW);
    attn_red1<<<dim3(16, G), 64, 0, stream>>>(pm, pl, pacc, m2, l2, acc2);
    attn_red2<<<1, 1024, 0, stream>>>(m2, l2, acc2, values, G);
    gemv_partial<<<dim3(4, 16), 256, 0, stream>>>(Wo, values, gp1);
    combine_ln<<<1, 1024, 0, stream>>>(gp1, bo, x, ln1s, ln1b, h1);
    gemv_partial<<<dim3(4, 16), 256, 0, stream>>>(W1, h1, gp2);
    combine_relu<<<1, 1024, 0, stream>>>(gp2, b1, hff);
    gemv_partial<<<dim3(4, 16), 256, 0, stream>>>(W2, hff, gp3);
    combine_ln<<<1, 1024, 0, stream>>>(gp3, b2, h1, ln2s, ln2b, out);
}